// Round 4
// baseline (558.702 us; speedup 1.0000x reference)
//
#include <hip/hip_runtime.h>
#include <cstddef>

namespace {

constexpr int IMG    = 256;
constexpr int TILE_R = 128;          // output rows per block
constexpr int TILE_C = 64;           // output cols per block
constexpr int BSTR   = 100;          // LDS row stride (floats); %32==4 -> banks rotate per row
constexpr int BROWS  = 162;          // rows 0..161 touched (reads up to start+4 = 161)
constexpr int BUFSZ  = BROWS * BSTR; // 16200 floats = 64.8 KB (single buffer)
constexpr int NTHR   = 960;          // 15 waves
constexpr int NCG    = 24;           // 24 col-groups * 4 cols = 96
constexpr int STRIP  = 4;            // rows per thread (40 teams * 4 = rows 1..160)
constexpr int STEPS  = 15;
constexpr int SROWS  = 159;          // staged rows 0..158
constexpr long long N_ELEM = 16LL * 8 * IMG * IMG;   // 8388608

constexpr float RP   = 3.9f;
constexpr float EPSF = 0.3f;
constexpr float OME  = 0.7f;    // 1 - EPS
constexpr float BET  = 0.15f;
constexpr float OMB  = 0.85f;   // 1 - BETA
constexpr float CLO  = 1e-4f;
constexpr float CHI  = (float)(1.0 - 1e-4);

__device__ __forceinline__ float mapf(float g) {
#pragma clang fp contract(off)
    float t = RP * g;          // match numpy op order: (R*g) * (1-g)
    float m = t * (1.0f - g);
    return m;
}

// guarded float4 load; y-guard always, x-guard only when CX (x is 0 mod 4).
template<bool CX>
__device__ __forceinline__ float4 load4yx(const float* __restrict__ im, int y, int x) {
    bool v = ((unsigned)y < (unsigned)IMG);
    if (CX) v = v && ((unsigned)x < (unsigned)IMG);
    const float* p = im + (v ? (y * IMG + x) : 0);
    float4 r = *(const float4*)p;
    if (!v) { r.x = 0.f; r.y = 0.f; r.z = 0.f; r.w = 0.f; }
    return r;
}

// read MAPPED row r: own quad via ds_read_b128, halos via lane shuffles.
// Wrong-row shuffle data lands only in dead validity margins; wave-boundary
// lanes with a live halo (fixL/fixR) take a 1-lane LDS read.
__device__ __forceinline__ void loadrow(const float* __restrict__ buf, int r, int c4,
                                        bool fixL, bool fixR, float w[6]) {
    const float* p = buf + r * BSTR + c4;
    float4 m = *(const float4*)p;   // ds_read_b128
    w[1] = m.x; w[2] = m.y; w[3] = m.z; w[4] = m.w;
    w[0] = __shfl_up(m.w, 1);       // lane-1's col c4-1
    w[5] = __shfl_down(m.x, 1);     // lane+1's col c4+4
    if (fixL) w[0] = p[-1];
    if (fixR) w[5] = p[4];
}

__device__ __forceinline__ float conv3(const float k[9], const float A[6], const float B[6],
                                       const float C[6], int j) {
    float a = k[0] * A[j];
    a = fmaf(k[1], A[j + 1], a);
    a = fmaf(k[2], A[j + 2], a);
    a = fmaf(k[3], B[j],     a);
    a = fmaf(k[4], B[j + 1], a);
    a = fmaf(k[5], B[j + 2], a);
    a = fmaf(k[6], C[j],     a);
    a = fmaf(k[7], C[j + 1], a);
    a = fmaf(k[8], C[j + 2], a);
    return a;
}

// one output row: A = mapped row r-1, B = row r, C = row r+1 (loaded here).
// Output STAGED into registers; LDS write happens after a barrier.
// dv re-read from global (L2/L3-hot) via precomputed safe offsets.
// F: final step -> stage raw g (for epilogue); else stage mapf(g)
#define ROW_BODY(i, A, B, C, F) {                                                \
    const int r_ = start + (i);                                                  \
    loadrow(buf, r_ + 1, c4, fixL, fixR, C);                                     \
    float4 dq_ = *(const float4*)(dimg + rowoff[i]);                             \
    const float lv_ = livef[i];                                                  \
    float go_[4];                                                                \
    float dd_[4] = {dq_.x, dq_.y, dq_.z, dq_.w};                                 \
    _Pragma("unroll")                                                            \
    for (int j = 0; j < 4; ++j) {                                                \
        float a_  = conv3(k, A, B, C, j);                                        \
        float ph_ = fmaf(EPSF, a_, OME * B[j + 1]);                              \
        float g_  = fmaf(BET, dd_[j], OMB * ph_);                                \
        g_ = fminf(fmaxf(g_, CLO), CHI);                                         \
        g_ = g_ * lv_;                                                           \
        sum[(i) * 4 + j] += g_;                                                  \
        sq[(i) * 4 + j]  = fmaf(g_, g_, sq[(i) * 4 + j]);                        \
        if (F) go_[j] = g_; else go_[j] = mapf(g_);                              \
    }                                                                            \
    stg[i].x = go_[0]; stg[i].y = go_[1]; stg[i].z = go_[2]; stg[i].w = go_[3];  \
}

#define STEP_COMPUTE(F) {                                                        \
    float w0[6], w1[6], w2[6];                                                   \
    loadrow(buf, start - 1, c4, fixL, fixR, w0);                                 \
    loadrow(buf, start,     c4, fixL, fixR, w1);                                 \
    ROW_BODY(0, w0, w1, w2, F)                                                   \
    ROW_BODY(1, w1, w2, w0, F)                                                   \
    ROW_BODY(2, w2, w0, w1, F)                                                   \
    ROW_BODY(3, w0, w1, w2, F)                                                   \
}

template<bool EX>
__device__ __forceinline__ void run_tile(const float* __restrict__ drive,
                                         const float* __restrict__ Kl,
                                         float* __restrict__ out,
                                         int img, int ty, int tx, float* buf)
{
    const int tid = threadIdx.x;
    const int cg  = (int)((unsigned)tid % (unsigned)NCG);
    const int rt  = (int)((unsigned)tid / (unsigned)NCG);
    const int c4  = cg * 4;
    const int start = 1 + rt * STRIP;
    const int lane = tid & 63;
    const bool fixL = (lane == 0)  && (cg != 0);
    const bool fixR = (lane == 63) && (cg != 23);

    const int ch = img & 7;
    float k[9];
#pragma unroll
    for (int i = 0; i < 9; ++i) k[i] = Kl[ch * 9 + i];

    const float* dimg = drive + (size_t)img * (IMG * IMG);
    const int y0 = ty * TILE_R - 16;   // image y of buffer row 0
    const int x0 = tx * TILE_C - 16;   // image x of buffer col 0
    const int xg = x0 + c4;
    const bool xok = ((unsigned)xg < (unsigned)IMG);

    // ---- stage g0 = drive, store MAPPED values (mapf(0)=0 keeps zero-pad)
#pragma unroll
    for (int it = 0; it < 4; ++it) {
        int task = tid + it * NTHR;
        if (task < SROWS * NCG) {
            int r = (int)((unsigned)task / (unsigned)NCG);
            int c = (int)((unsigned)task % (unsigned)NCG) * 4;
            float4 v = load4yx<EX>(dimg, y0 + r, x0 + c);
            float4 m; m.x = mapf(v.x); m.y = mapf(v.y); m.z = mapf(v.z); m.w = mapf(v.w);
            *(float4*)(buf + r * BSTR + c) = m;
        }
    }

    // ---- per-row liveness + safe drive offsets (reused all steps + epilogue)
    float livef[STRIP];
    int rowoff[STRIP];
#pragma unroll
    for (int i = 0; i < STRIP; ++i) {
        const int y = y0 + start + i;
        bool ok = ((unsigned)y < (unsigned)IMG);
        if (EX) ok = ok && xok;
        livef[i]  = ok ? 1.0f : 0.0f;
        rowoff[i] = ok ? (y * IMG + xg) : 0;
    }

    float sum[STRIP * 4], sq[STRIP * 4];
#pragma unroll
    for (int i = 0; i < STRIP * 4; ++i) { sum[i] = 0.f; sq[i] = 0.f; }

    float4 stg[STRIP];

    __syncthreads();

    // steps 0..13: compute into registers, barrier, write in place, barrier
    for (int s = 0; s < STEPS - 1; ++s) {
        STEP_COMPUTE(0)
        __syncthreads();
#pragma unroll
        for (int i = 0; i < STRIP; ++i)
            *(float4*)(buf + (start + i) * BSTR + c4) = stg[i];
        __syncthreads();
    }
    // final step: compute only (raw g stays in stg); epilogue is register-only
    STEP_COMPUTE(1)

    // ---- epilogue: each thread owns its strip's inner pixels (regs + L2 dv)
    const bool colin = (c4 >= 16) && (c4 <= 76);
    const float inv15 = 1.0f / 15.0f;

#pragma unroll
    for (int i = 0; i < STRIP; ++i) {
        const int r = start + i;
        const bool rowin = (r >= 16) && (r <= 16 + TILE_R - 1);
        if (colin && rowin) {
            const int y = y0 + r;
            const int x = xg;
            float4 dvv = *(const float4*)(dimg + rowoff[i]);
            float gg[4] = {stg[i].x, stg[i].y, stg[i].z, stg[i].w};
            float dd[4] = {dvv.x, dvv.y, dvv.z, dvv.w};
            float mn[4], vr[4], dl[4];
#pragma unroll
            for (int j = 0; j < 4; ++j) {
                float m = sum[i * 4 + j] * inv15;
                float v = fmaf(-m, m, sq[i * 4 + j] * inv15);
                vr[j] = fmaxf(v, 0.0f);
                mn[j] = m;
                dl[j] = gg[j] - dd[j];
            }
            size_t base = (size_t)img * (IMG * IMG) + (size_t)y * IMG + x;
            float4 g4; g4.x = gg[0]; g4.y = gg[1]; g4.z = gg[2]; g4.w = gg[3];
            float4 m4; m4.x = mn[0]; m4.y = mn[1]; m4.z = mn[2]; m4.w = mn[3];
            float4 v4; v4.x = vr[0]; v4.y = vr[1]; v4.z = vr[2]; v4.w = vr[3];
            float4 d4; d4.x = dl[0]; d4.y = dl[1]; d4.z = dl[2]; d4.w = dl[3];
            *(float4*)(out + 0 * N_ELEM + base) = g4;   // last
            *(float4*)(out + 1 * N_ELEM + base) = m4;   // mean
            *(float4*)(out + 2 * N_ELEM + base) = v4;   // var
            *(float4*)(out + 3 * N_ELEM + base) = d4;   // delta
            *(float4*)(out + 4 * N_ELEM + base) = d4;   // last_drive
        }
    }
}

__global__ __launch_bounds__(NTHR, 6)
void cml_kernel(const float* __restrict__ drive,
                const float* __restrict__ Kl,
                float* __restrict__ out)
{
    __shared__ __align__(16) float lds[BUFSZ + 8];   // 64832 B <= 64 KB+pad limit
    const int bx  = blockIdx.x;
    const int img = bx >> 3;         // 0..127  (b*8 + c)
    const int t   = bx & 7;
    const int ty  = t >> 2;          // 0..1  (128-row tiles)
    const int tx  = t & 3;           // 0..3  (64-col tiles)
    const bool ex = (tx == 0) | (tx == 3);
    if (ex) run_tile<true >(drive, Kl, out, img, ty, tx, lds);
    else    run_tile<false>(drive, Kl, out, img, ty, tx, lds);
}

} // namespace

extern "C" void kernel_launch(void* const* d_in, const int* in_sizes, int n_in,
                              void* d_out, int out_size, void* d_ws, size_t ws_size,
                              hipStream_t stream) {
    const float* drive = (const float*)d_in[0];
    const float* Kl    = (const float*)d_in[1];
    float* out         = (float*)d_out;
    (void)in_sizes; (void)n_in; (void)out_size; (void)d_ws; (void)ws_size;

    dim3 grid(128 * 8);   // 128 images * 8 tiles (128x64)
    dim3 block(NTHR);
    cml_kernel<<<grid, block, 0, stream>>>(drive, Kl, out);
}

// Round 5
// 189.757 us; speedup vs baseline: 2.9443x; 2.9443x over previous
//
#include <hip/hip_runtime.h>
#include <cstddef>

namespace {

constexpr int IMG    = 256;
constexpr int TILE_R = 128;          // output rows per block
constexpr int TILE_C = 64;           // output cols per block
constexpr int BSTR   = 100;          // LDS row stride (floats); %32==4 -> banks rotate per row
constexpr int BROWS  = 162;          // rows 0..161 touched (reads up to start+4 = 161)
constexpr int BUFSZ  = BROWS * BSTR; // 16200 floats = 64.8 KB (single buffer)
constexpr int NTHR   = 960;          // 15 waves
constexpr int NCG    = 24;           // 24 col-groups * 4 cols = 96
constexpr int STRIP  = 4;            // rows per thread (40 teams * 4 = rows 1..160)
constexpr int STEPS  = 15;
constexpr int SROWS  = 159;          // staged rows 0..158 (159..161 = confined dead margin)
constexpr long long N_ELEM = 16LL * 8 * IMG * IMG;   // 8388608

constexpr float RP   = 3.9f;
constexpr float EPSF = 0.3f;
constexpr float OME  = 0.7f;    // 1 - EPS
constexpr float BET  = 0.15f;
constexpr float OMB  = 0.85f;   // 1 - BETA
constexpr float CLO  = 1e-4f;
constexpr float CHI  = (float)(1.0 - 1e-4);

__device__ __forceinline__ float mapf(float g) {
#pragma clang fp contract(off)
    float t = RP * g;          // match numpy op order: (R*g) * (1-g)
    float m = t * (1.0f - g);
    return m;
}

// guarded float4 load; y-guard always, x-guard only when CX (x is 0 mod 4).
template<bool CX>
__device__ __forceinline__ float4 load4yx(const float* __restrict__ im, int y, int x) {
    bool v = ((unsigned)y < (unsigned)IMG);
    if (CX) v = v && ((unsigned)x < (unsigned)IMG);
    const float* p = im + (v ? (y * IMG + x) : 0);
    float4 r = *(const float4*)p;
    if (!v) { r.x = 0.f; r.y = 0.f; r.z = 0.f; r.w = 0.f; }
    return r;
}

// read MAPPED row r: own quad via ds_read_b128, halos via lane shuffles.
// Wrong-row shuffle data lands only in dead validity margins; wave-boundary
// lanes with a live halo (fixL/fixR) take a 1-lane LDS read.
__device__ __forceinline__ void loadrow(const float* __restrict__ buf, int r, int c4,
                                        bool fixL, bool fixR, float w[6]) {
    const float* p = buf + r * BSTR + c4;
    float4 m = *(const float4*)p;   // ds_read_b128
    w[1] = m.x; w[2] = m.y; w[3] = m.z; w[4] = m.w;
    w[0] = __shfl_up(m.w, 1);       // lane-1's col c4-1
    w[5] = __shfl_down(m.x, 1);     // lane+1's col c4+4
    if (fixL) w[0] = p[-1];
    if (fixR) w[5] = p[4];
}

__device__ __forceinline__ float conv3(const float k[9], const float A[6], const float B[6],
                                       const float C[6], int j) {
    float a = k[0] * A[j];
    a = fmaf(k[1], A[j + 1], a);
    a = fmaf(k[2], A[j + 2], a);
    a = fmaf(k[3], B[j],     a);
    a = fmaf(k[4], B[j + 1], a);
    a = fmaf(k[5], B[j + 2], a);
    a = fmaf(k[6], C[j],     a);
    a = fmaf(k[7], C[j + 1], a);
    a = fmaf(k[8], C[j + 2], a);
    return a;
}

// one output row: A = mapped row r-1, B = row r, C = row r+1 (loaded here).
// Output STAGED into registers; LDS write happens after a barrier.
// F: final step -> stage raw g (for epilogue); else stage mapf(g)
#define ROW_BODY(i, A, B, C, F) {                                                \
    const int r_ = start + (i);                                                  \
    loadrow(buf, r_ + 1, c4, fixL, fixR, C);                                     \
    const float lv_ = livef[i];                                                  \
    float go_[4];                                                                \
    _Pragma("unroll")                                                            \
    for (int j = 0; j < 4; ++j) {                                                \
        float a_  = conv3(k, A, B, C, j);                                        \
        float ph_ = fmaf(EPSF, a_, OME * B[j + 1]);                              \
        float g_  = fmaf(BET, dv[(i) * 4 + j], OMB * ph_);                       \
        g_ = fminf(fmaxf(g_, CLO), CHI);                                         \
        g_ = g_ * lv_;                                                           \
        sum[(i) * 4 + j] += g_;                                                  \
        sq[(i) * 4 + j]  = fmaf(g_, g_, sq[(i) * 4 + j]);                        \
        if (F) go_[j] = g_; else go_[j] = mapf(g_);                              \
    }                                                                            \
    stg[i].x = go_[0]; stg[i].y = go_[1]; stg[i].z = go_[2]; stg[i].w = go_[3];  \
}

#define STEP_COMPUTE(F) {                                                        \
    float w0[6], w1[6], w2[6];                                                   \
    loadrow(buf, start - 1, c4, fixL, fixR, w0);                                 \
    loadrow(buf, start,     c4, fixL, fixR, w1);                                 \
    ROW_BODY(0, w0, w1, w2, F)                                                   \
    ROW_BODY(1, w1, w2, w0, F)                                                   \
    ROW_BODY(2, w2, w0, w1, F)                                                   \
    ROW_BODY(3, w0, w1, w2, F)                                                   \
}

template<bool EX>
__device__ __forceinline__ void run_tile(const float* __restrict__ drive,
                                         const float* __restrict__ Kl,
                                         float* __restrict__ out,
                                         int img, int ty, int tx, float* buf)
{
    const int tid = threadIdx.x;
    const int cg  = (int)((unsigned)tid % (unsigned)NCG);
    const int rt  = (int)((unsigned)tid / (unsigned)NCG);
    const int c4  = cg * 4;
    const int start = 1 + rt * STRIP;
    const int lane = tid & 63;
    const bool fixL = (lane == 0)  && (cg != 0);
    const bool fixR = (lane == 63) && (cg != 23);

    const int ch = img & 7;
    float k[9];
#pragma unroll
    for (int i = 0; i < 9; ++i) k[i] = Kl[ch * 9 + i];

    const float* dimg = drive + (size_t)img * (IMG * IMG);
    const int y0 = ty * TILE_R - 16;   // image y of buffer row 0
    const int x0 = tx * TILE_C - 16;   // image x of buffer col 0
    const int xg = x0 + c4;
    const bool xok = ((unsigned)xg < (unsigned)IMG);

    // ---- stage g0 = drive, store MAPPED values (mapf(0)=0 keeps zero-pad)
#pragma unroll
    for (int it = 0; it < 4; ++it) {
        int task = tid + it * NTHR;
        if (task < SROWS * NCG) {
            int r = (int)((unsigned)task / (unsigned)NCG);
            int c = (int)((unsigned)task % (unsigned)NCG) * 4;
            float4 v = load4yx<EX>(dimg, y0 + r, x0 + c);
            float4 m; m.x = mapf(v.x); m.y = mapf(v.y); m.z = mapf(v.z); m.w = mapf(v.w);
            *(float4*)(buf + r * BSTR + c) = m;
        }
    }

    // ---- own drive pixels + liveness -> registers (reused all steps + epilogue)
    float dv[STRIP * 4];
    float livef[STRIP];
#pragma unroll
    for (int i = 0; i < STRIP; ++i) {
        const int y = y0 + start + i;
        bool ok = ((unsigned)y < (unsigned)IMG);
        if (EX) ok = ok && xok;
        livef[i] = ok ? 1.0f : 0.0f;
        float4 t = load4yx<EX>(dimg, y, xg);
        dv[i * 4 + 0] = t.x; dv[i * 4 + 1] = t.y;
        dv[i * 4 + 2] = t.z; dv[i * 4 + 3] = t.w;
    }

    float sum[STRIP * 4], sq[STRIP * 4];
#pragma unroll
    for (int i = 0; i < STRIP * 4; ++i) { sum[i] = 0.f; sq[i] = 0.f; }

    float4 stg[STRIP];

    __syncthreads();

    // steps 0..13: compute into registers, barrier, write in place, barrier
    for (int s = 0; s < STEPS - 1; ++s) {
        STEP_COMPUTE(0)
        __syncthreads();
#pragma unroll
        for (int i = 0; i < STRIP; ++i)
            *(float4*)(buf + (start + i) * BSTR + c4) = stg[i];
        __syncthreads();
    }
    // final step: compute only (raw g stays in stg); epilogue is register-only
    STEP_COMPUTE(1)

    // ---- epilogue: each thread owns its strip's inner pixels (all in regs)
    const bool colin = (c4 >= 16) && (c4 <= 76);
    const float inv15 = 1.0f / 15.0f;

#pragma unroll
    for (int i = 0; i < STRIP; ++i) {
        const int r = start + i;
        const bool rowin = (r >= 16) && (r <= 16 + TILE_R - 1);
        if (colin && rowin) {
            const int y = y0 + r;
            const int x = xg;
            float gg[4] = {stg[i].x, stg[i].y, stg[i].z, stg[i].w};
            float mn[4], vr[4], dl[4];
#pragma unroll
            for (int j = 0; j < 4; ++j) {
                float m = sum[i * 4 + j] * inv15;
                float v = fmaf(-m, m, sq[i * 4 + j] * inv15);
                vr[j] = fmaxf(v, 0.0f);
                mn[j] = m;
                dl[j] = gg[j] - dv[i * 4 + j];
            }
            size_t base = (size_t)img * (IMG * IMG) + (size_t)y * IMG + x;
            float4 g4; g4.x = gg[0]; g4.y = gg[1]; g4.z = gg[2]; g4.w = gg[3];
            float4 m4; m4.x = mn[0]; m4.y = mn[1]; m4.z = mn[2]; m4.w = mn[3];
            float4 v4; v4.x = vr[0]; v4.y = vr[1]; v4.z = vr[2]; v4.w = vr[3];
            float4 d4; d4.x = dl[0]; d4.y = dl[1]; d4.z = dl[2]; d4.w = dl[3];
            *(float4*)(out + 0 * N_ELEM + base) = g4;   // last
            *(float4*)(out + 1 * N_ELEM + base) = m4;   // mean
            *(float4*)(out + 2 * N_ELEM + base) = v4;   // var
            *(float4*)(out + 3 * N_ELEM + base) = d4;   // delta
            *(float4*)(out + 4 * N_ELEM + base) = d4;   // last_drive
        }
    }
}

__global__ __launch_bounds__(NTHR, 4)   // 4 waves/EU = 1 WG of 15 waves; VGPR cap 128
void cml_kernel(const float* __restrict__ drive,
                const float* __restrict__ Kl,
                float* __restrict__ out)
{
    __shared__ __align__(16) float lds[BUFSZ + 8];   // 64832 B
    const int bx  = blockIdx.x;
    const int img = bx >> 3;         // 0..127  (b*8 + c)
    const int t   = bx & 7;
    const int ty  = t >> 2;          // 0..1  (128-row tiles)
    const int tx  = t & 3;           // 0..3  (64-col tiles)
    const bool ex = (tx == 0) | (tx == 3);
    if (ex) run_tile<true >(drive, Kl, out, img, ty, tx, lds);
    else    run_tile<false>(drive, Kl, out, img, ty, tx, lds);
}

} // namespace

extern "C" void kernel_launch(void* const* d_in, const int* in_sizes, int n_in,
                              void* d_out, int out_size, void* d_ws, size_t ws_size,
                              hipStream_t stream) {
    const float* drive = (const float*)d_in[0];
    const float* Kl    = (const float*)d_in[1];
    float* out         = (float*)d_out;
    (void)in_sizes; (void)n_in; (void)out_size; (void)d_ws; (void)ws_size;

    dim3 grid(128 * 8);   // 128 images * 8 tiles (128x64)
    dim3 block(NTHR);
    cml_kernel<<<grid, block, 0, stream>>>(drive, Kl, out);
}